// Round 5
// baseline (74.208 us; speedup 1.0000x reference)
//
#include <hip/hip_runtime.h>

#define LL     4096
#define OUTL   8191
#define FPAD   272            // fwd zero-pad low side
#define NPAIRF 2340           // pairs (dwords) per fwd copy
#define CSTRF  2952           // phys dwords per fwd copy (>=2925, mod 32 == 8)
#define REVB   11808          // 4*CSTRF, 16B aligned
#define BTOP   5895           // rev copy top x-index (== 7 mod 8)
#define NG     968            // rev 16B units (covers x-idx [-1849..5895])
#define LDS_DW 15680          // REVB + 3872

typedef short v8s __attribute__((ext_vector_type(8)));
typedef float v4f __attribute__((ext_vector_type(4)));

__device__ __forceinline__ unsigned bf16b(float f) {
    unsigned u = __builtin_bit_cast(unsigned, f);
    u += 0x7fff + ((u >> 16) & 1);          // RNE
    return u >> 16;
}
__device__ __forceinline__ int physdw(int r, int p) { return r * CSTRF + p + 2 * (p >> 3); }
__device__ __forceinline__ int revdw(int g) { return REVB + 4 * (g ^ ((g >> 3) & 7)); }

struct Frag { uint2 a0l, a0h, a1l, a1h; uint4 b0, b1, b2, b3; };

__global__ __launch_bounds__(256)
void selfconv_mfma3(const float* __restrict__ xg, float* __restrict__ outg) {
    __shared__ unsigned lds[LDS_DW];
    const int tid = threadIdx.x;
    const int blk = blockIdx.x;
    // (b, b+256) pairs balance: regions {0,1} in first half, {2,3} in second
    const int h2 = blk >> 8;
    const int b  = (blk & 255) >> 1;
    const int rg = (blk & 1) + 2 * h2;
    const int T0 = rg << 11;               // 2048-output region
    const float* __restrict__ xb = xg + b * LL;

    // ---- stage 4 parity-shifted fwd bf16 copies (b64 writes) ----
    for (int r = 0; r < 4; ++r)
        for (int pp = tid; pp < NPAIRF / 2; pp += 256) {
            int p = 2 * pp;
            int e = 4 * pp + r - FPAD;
            float f0 = (e >= 0 && e < LL) ? xb[e] : 0.f;
            float f1 = (e + 1 >= 0 && e + 1 < LL) ? xb[e + 1] : 0.f;
            float f2 = (e + 2 >= 0 && e + 2 < LL) ? xb[e + 2] : 0.f;
            float f3 = (e + 3 >= 0 && e + 3 < LL) ? xb[e + 3] : 0.f;
            uint2 w;
            w.x = bf16b(f0) | (bf16b(f1) << 16);
            w.y = bf16b(f2) | (bf16b(f3) << 16);
            *(uint2*)&lds[physdw(r, p)] = w;
        }
    // ---- stage reversed copy: yr[e'] = x[BTOP - e'] (b128 writes) ----
    for (int g = tid; g < NG; g += 256) {
        unsigned w[4];
#pragma unroll
        for (int d = 0; d < 4; ++d) {
            int xlo = BTOP - (8 * g + 2 * d);
            int xhi = xlo - 1;
            float flo = (xlo >= 0 && xlo < LL) ? xb[xlo] : 0.f;
            float fhi = (xhi >= 0 && xhi < LL) ? xb[xhi] : 0.f;
            w[d] = bf16b(flo) | (bf16b(fhi) << 16);
        }
        *(uint4*)&lds[revdw(g)] = uint4{w[0], w[1], w[2], w[3]};
    }
    __syncthreads();

    const int wv   = tid >> 6;
    const int lane = tid & 63;
    const int ln16 = lane & 15;
    const int q    = lane >> 4;

    // i-union over the 8 tiles (u<2 via A +256u, v<4 via B +512v)
    int mn = 0x7fffffff, mx = -0x7fffffff;
#pragma unroll
    for (int u = 0; u < 2; ++u)
#pragma unroll
        for (int v = 0; v < 4; ++v) {
            int base = T0 + 256 * u + 512 * v;
            int iLo = base - (LL - 1); if (iLo < 0) iLo = 0;
            int iHi = base + 255;      if (iHi > LL - 1) iHi = LL - 1;
            int a = iLo - 256 * u; if (a < mn) mn = a;
            int c2 = iHi - 256 * u; if (c2 > mx) mx = c2;
        }
    const int base_   = mn - 15;
    const int i0start = base_ - ((base_ - 1) & 7);   // == 1 mod 8 (B 16B-align)
    const int nch     = ((mx - i0start) >> 5) + 1;
    const int nw      = (nch - wv + 3) >> 2;         // 4-way i-split by chunk id
    const int cmax    = nw - 1;
    const int i0w     = i0start + 32 * wv;

    // A fragment base (R3/R4-proven): A[m=ln16][k=8q+j] = x[i0 + m + 8q + j]
    int uA = i0w + ln16 + 8 * q + FPAD;
    int rA = uA & 3, pA = (uA >> 2) << 1;
    const int awA0 = physdw(rA, pA), awA1 = physdw(rA, pA + 2);
    // B base: B_v[8q+j][n=ln16] = yr[sR + j], sR = BTOP - (T0+512v) + i0 - 16n + 8q
    const int gB0 = ((BTOP - T0 + i0w) >> 3) - 2 * ln16 + q;

    v4f acc00{0,0,0,0}, acc01{0,0,0,0}, acc02{0,0,0,0}, acc03{0,0,0,0};
    v4f acc10{0,0,0,0}, acc11{0,0,0,0}, acc12{0,0,0,0}, acc13{0,0,0,0};

    auto ld = [&](Frag& F, int c) {
        int ic = c > cmax ? cmax : c;
        int oA = 80 * ic;                       // 128 elems per wave-chunk
        F.a0l = *(const uint2*)&lds[awA0 + oA];
        F.a0h = *(const uint2*)&lds[awA1 + oA];
        F.a1l = *(const uint2*)&lds[awA0 + oA + 160];
        F.a1h = *(const uint2*)&lds[awA1 + oA + 160];
        int g = gB0 + 16 * ic;
        F.b0 = *(const uint4*)&lds[revdw(g)];
        F.b1 = *(const uint4*)&lds[revdw(g - 64)];
        F.b2 = *(const uint4*)&lds[revdw(g - 128)];
        F.b3 = *(const uint4*)&lds[revdw(g - 192)];
    };
    auto mk2 = [](uint2 lo, uint2 hi) {
        union { unsigned u[4]; v8s s; } z;
        z.u[0] = lo.x; z.u[1] = lo.y; z.u[2] = hi.x; z.u[3] = hi.y; return z.s;
    };
    auto mk4 = [](uint4 v) {
        union { unsigned u[4]; v8s s; } z;
        z.u[0] = v.x; z.u[1] = v.y; z.u[2] = v.z; z.u[3] = v.w; return z.s;
    };
    auto cmp = [&](const Frag& F) {
        v8s A0 = mk2(F.a0l, F.a0h), A1 = mk2(F.a1l, F.a1h);
        v8s B0 = mk4(F.b0), B1 = mk4(F.b1), B2 = mk4(F.b2), B3 = mk4(F.b3);
        acc00 = __builtin_amdgcn_mfma_f32_16x16x32_bf16(A0, B0, acc00, 0, 0, 0);
        acc10 = __builtin_amdgcn_mfma_f32_16x16x32_bf16(A1, B0, acc10, 0, 0, 0);
        acc01 = __builtin_amdgcn_mfma_f32_16x16x32_bf16(A0, B1, acc01, 0, 0, 0);
        acc11 = __builtin_amdgcn_mfma_f32_16x16x32_bf16(A1, B1, acc11, 0, 0, 0);
        acc02 = __builtin_amdgcn_mfma_f32_16x16x32_bf16(A0, B2, acc02, 0, 0, 0);
        acc12 = __builtin_amdgcn_mfma_f32_16x16x32_bf16(A1, B2, acc12, 0, 0, 0);
        acc03 = __builtin_amdgcn_mfma_f32_16x16x32_bf16(A0, B3, acc03, 0, 0, 0);
        acc13 = __builtin_amdgcn_mfma_f32_16x16x32_bf16(A1, B3, acc13, 0, 0, 0);
    };

    Frag F0, F1, F2;
    ld(F0, 0); ld(F1, 1);               // nw >= 16 always
    int c = 0;
    for (; c + 3 <= nw; c += 3) {       // 3-deep pipeline
        ld(F2, c + 2); cmp(F0);
        ld(F0, c + 3); cmp(F1);
        ld(F1, c + 4); cmp(F2);
    }
    if (c < nw)     cmp(F0);
    if (c + 1 < nw) cmp(F1);

    // ---- 4-way reduction through LDS (stride 36 breaks pow-2 banks) ----
    __syncthreads();
    float* fs = (float*)lds;
    if (wv > 0) {
        int sb = ((wv - 1) * 64 + lane) * 36;
        *(v4f*)&fs[sb]      = acc00; *(v4f*)&fs[sb + 4]  = acc10;
        *(v4f*)&fs[sb + 8]  = acc01; *(v4f*)&fs[sb + 12] = acc11;
        *(v4f*)&fs[sb + 16] = acc02; *(v4f*)&fs[sb + 20] = acc12;
        *(v4f*)&fs[sb + 24] = acc03; *(v4f*)&fs[sb + 28] = acc13;
    }
    __syncthreads();
    if (wv == 0) {
#pragma unroll
        for (int s = 0; s < 3; ++s) {
            int sb = (s * 64 + lane) * 36;
            acc00 += *(const v4f*)&fs[sb];      acc10 += *(const v4f*)&fs[sb + 4];
            acc01 += *(const v4f*)&fs[sb + 8];  acc11 += *(const v4f*)&fs[sb + 12];
            acc02 += *(const v4f*)&fs[sb + 16]; acc12 += *(const v4f*)&fs[sb + 20];
            acc03 += *(const v4f*)&fs[sb + 24]; acc13 += *(const v4f*)&fs[sb + 28];
        }
        float* __restrict__ ob = outg + b * OUTL;
        const v4f* accs[8] = {&acc00, &acc10, &acc01, &acc11,
                              &acc02, &acc12, &acc03, &acc13};
#pragma unroll
        for (int uv = 0; uv < 8; ++uv) {
            int u = uv & 1, v = uv >> 1;
            int tb = T0 + 256 * u + 512 * v + 4 * q + 16 * ln16;
            v4f a = *accs[uv];
#pragma unroll
            for (int r2 = 0; r2 < 4; ++r2)
                if (tb + r2 < OUTL) ob[tb + r2] = a[r2];
        }
    }
}

extern "C" void kernel_launch(void* const* d_in, const int* in_sizes, int n_in,
                              void* d_out, int out_size, void* d_ws, size_t ws_size,
                              hipStream_t stream) {
    const float* x = (const float*)d_in[0];
    float* out = (float*)d_out;
    selfconv_mfma3<<<dim3(512), dim3(256), 0, stream>>>(x, out);
}

// Round 7
// 65.207 us; speedup vs baseline: 1.1380x; 1.1380x over previous
//
#include <hip/hip_runtime.h>

#define LL    4096
#define OUTL  8191
#define FPAD  272
#define NPDW  2336          // dwords per fwd copy: elements -272..4399 (A1 needs <=4383)
#define CB1   2352          // copy1 base dword (16-dword bank stagger)
#define RB    4704          // rev-copy base dword (16B aligned)
#define BTOP  5887          // rev top x-index (== 7 mod 8)
#define NGU   971           // rev 8-elem units (e' in [0, 7767]; need <=7695)
#define LDSDW 9472          // 37.9 KB; rev ends 8588, reduce scratch ends 9212

typedef short v8s __attribute__((ext_vector_type(8)));
typedef float v4f __attribute__((ext_vector_type(4)));

__device__ __forceinline__ unsigned bf16b(float f) {
    unsigned u = __builtin_bit_cast(unsigned, f);
    u += 0x7fff + ((u >> 16) & 1);          // RNE
    return u >> 16;
}

struct Frag { unsigned a[4], a2[4]; uint4 b3, b2, b1, b0; };

__global__ __launch_bounds__(512, 4)
void selfconv_mfma5(const float* __restrict__ xg, float* __restrict__ outg) {
    __shared__ unsigned lds[LDSDW];
    const int tid = threadIdx.x;
    const int blk = blockIdx.x;
    const int b   = blk & 127;
    const int id  = blk >> 7;                       // dispatch-order balance:
    const int rg  = (id == 0) ? 0 : (id == 1) ? 3 : (id == 2) ? 1 : 2;
    const int T0  = rg << 11;                       // 2048-output region
    const float* __restrict__ xb = xg + b * LL;

    // ---- fwd copies r=0,1: dword p = pack(x[2p+r-272], x[2p+r-271]) ----
    for (int idx = tid; idx < 2 * NPDW; idx += 512) {
        int r = idx >= NPDW ? 1 : 0;
        int p = idx - r * NPDW;
        int e = 2 * p + r - FPAD;
        float f0 = (e >= 0 && e < LL) ? xb[e] : 0.f;
        float f1 = (e + 1 >= 0 && e + 1 < LL) ? xb[e + 1] : 0.f;
        lds[(r ? CB1 : 0) + p] = bf16b(f0) | (bf16b(f1) << 16);
    }
    // ---- rev copy, 8-elem (16B) units, parity-XOR swizzle ----
    for (int g = tid; g < NGU; g += 512) {
        unsigned w[4];
#pragma unroll
        for (int d = 0; d < 4; ++d) {
            int xlo = BTOP - 8 * g - 2 * d;
            int xhi = xlo - 1;
            float flo = (xlo >= 0 && xlo < LL) ? xb[xlo] : 0.f;
            float fhi = (xhi >= 0 && xhi < LL) ? xb[xhi] : 0.f;
            w[d] = bf16b(flo) | (bf16b(fhi) << 16);
        }
        int P = g ^ ((g >> 4) & 1);
        *(uint4*)&lds[RB + 4 * P] = uint4{w[0], w[1], w[2], w[3]};
    }
    __syncthreads();

    const int wv = tid >> 6, lane = tid & 63, ln16 = lane & 15, q = lane >> 4;

    // i-union over the 8 tiles (A +256u, B +512v)
    int mn = 0x7fffffff, mx = -0x7fffffff;
#pragma unroll
    for (int u = 0; u < 2; ++u)
#pragma unroll
        for (int v = 0; v < 4; ++v) {
            int base = T0 + 256 * u + 512 * v;
            int iLo = base - (LL - 1); if (iLo < 0) iLo = 0;
            int iHi = base + 255;      if (iHi > LL - 1) iHi = LL - 1;
            int a = iLo - 256 * u; if (a < mn) mn = a;
            int c2 = iHi - 256 * u; if (c2 > mx) mx = c2;
        }
    const int base_   = mn - 15;
    const int i0start = base_ - ((base_ - 1) & 7);   // == 1 mod 8
    const int nch     = ((mx - i0start) >> 5) + 1;
    const int nw      = (nch - wv + 7) >> 3;         // 8-way interleaved split
    const int i0w     = i0start + 32 * wv;

    // A: x[i0 + m + 8q + j], m=ln16 — dword-parity copy select
    const int s0p = i0w + ln16 + 8 * q + FPAD;
    int aw = (s0p >> 1) + ((s0p & 1) ? CB1 : 0);
    // B: yr unit base at v=3 (smallest e'); loop strides preserve the XOR key
    const int g3 = (BTOP - T0 - 1536 - 16 * ln16 + i0w + 8 * q) >> 3;
    int bw = RB + 4 * (g3 ^ ((g3 >> 4) & 1));

    v4f a00{0,0,0,0}, a01{0,0,0,0}, a02{0,0,0,0}, a03{0,0,0,0};
    v4f a10{0,0,0,0}, a11{0,0,0,0}, a12{0,0,0,0}, a13{0,0,0,0};

    auto ld = [&](Frag& F, int a, int w) {
        F.a[0]  = lds[a];       F.a[1]  = lds[a + 1];
        F.a[2]  = lds[a + 2];   F.a[3]  = lds[a + 3];
        F.a2[0] = lds[a + 128]; F.a2[1] = lds[a + 129];   // +256 elements
        F.a2[2] = lds[a + 130]; F.a2[3] = lds[a + 131];
        F.b3 = *(const uint4*)&lds[w];
        F.b2 = *(const uint4*)&lds[w + 256];
        F.b1 = *(const uint4*)&lds[w + 512];
        F.b0 = *(const uint4*)&lds[w + 768];
    };
    auto mkA = [](const unsigned (&u)[4]) {
        union { unsigned x[4]; v8s s; } z;
        z.x[0] = u[0]; z.x[1] = u[1]; z.x[2] = u[2]; z.x[3] = u[3]; return z.s;
    };
    auto mkB = [](uint4 v) {
        union { unsigned x[4]; v8s s; } z;
        z.x[0] = v.x; z.x[1] = v.y; z.x[2] = v.z; z.x[3] = v.w; return z.s;
    };
    auto cmp = [&](const Frag& F) {
        v8s A0 = mkA(F.a), A1 = mkA(F.a2);
        v8s B0 = mkB(F.b0), B1 = mkB(F.b1), B2 = mkB(F.b2), B3 = mkB(F.b3);
        a00 = __builtin_amdgcn_mfma_f32_16x16x32_bf16(A0, B0, a00, 0, 0, 0);
        a10 = __builtin_amdgcn_mfma_f32_16x16x32_bf16(A1, B0, a10, 0, 0, 0);
        a01 = __builtin_amdgcn_mfma_f32_16x16x32_bf16(A0, B1, a01, 0, 0, 0);
        a11 = __builtin_amdgcn_mfma_f32_16x16x32_bf16(A1, B1, a11, 0, 0, 0);
        a02 = __builtin_amdgcn_mfma_f32_16x16x32_bf16(A0, B2, a02, 0, 0, 0);
        a12 = __builtin_amdgcn_mfma_f32_16x16x32_bf16(A1, B2, a12, 0, 0, 0);
        a03 = __builtin_amdgcn_mfma_f32_16x16x32_bf16(A0, B3, a03, 0, 0, 0);
        a13 = __builtin_amdgcn_mfma_f32_16x16x32_bf16(A1, B3, a13, 0, 0, 0);
    };

    // wave-chunk = 8 global chunks = 256 elements = 128 dwords (A and B alike)
    Frag F0, F1;
    int awE = aw, bwE = bw, awO = aw + 128, bwO = bw + 128;
    ld(F0, awE, bwE); awE += 256; bwE += 256;
    ld(F1, awO, bwO); awO += 256; bwO += 256;
    int c = 0;
    for (; c + 2 < nw; c += 2) {
        cmp(F0); ld(F0, awE, bwE); awE += 256; bwE += 256;
        cmp(F1); ld(F1, awO, bwO); awO += 256; bwO += 256;
    }
    cmp(F0);
    if (c + 1 < nw) cmp(F1);

    // ---- 8-way reduction (3 stages), stride-36 scratch ----
    float* fs = (float*)lds;
    __syncthreads();
    if (wv >= 4) {
        int sb = (wv - 4) * 2304 + lane * 36;
        *(v4f*)&fs[sb]      = a00; *(v4f*)&fs[sb + 4]  = a10;
        *(v4f*)&fs[sb + 8]  = a01; *(v4f*)&fs[sb + 12] = a11;
        *(v4f*)&fs[sb + 16] = a02; *(v4f*)&fs[sb + 20] = a12;
        *(v4f*)&fs[sb + 24] = a03; *(v4f*)&fs[sb + 28] = a13;
    }
    __syncthreads();
    if (wv < 4) {
        int sb = wv * 2304 + lane * 36;
        a00 += *(const v4f*)&fs[sb];      a10 += *(const v4f*)&fs[sb + 4];
        a01 += *(const v4f*)&fs[sb + 8];  a11 += *(const v4f*)&fs[sb + 12];
        a02 += *(const v4f*)&fs[sb + 16]; a12 += *(const v4f*)&fs[sb + 20];
        a03 += *(const v4f*)&fs[sb + 24]; a13 += *(const v4f*)&fs[sb + 28];
    }
    __syncthreads();
    if (wv >= 1 && wv < 4) {
        int sb = (wv - 1) * 2304 + lane * 36;
        *(v4f*)&fs[sb]      = a00; *(v4f*)&fs[sb + 4]  = a10;
        *(v4f*)&fs[sb + 8]  = a01; *(v4f*)&fs[sb + 12] = a11;
        *(v4f*)&fs[sb + 16] = a02; *(v4f*)&fs[sb + 20] = a12;
        *(v4f*)&fs[sb + 24] = a03; *(v4f*)&fs[sb + 28] = a13;
    }
    __syncthreads();
    if (wv == 0) {
#pragma unroll
        for (int s = 0; s < 3; ++s) {
            int sb = s * 2304 + lane * 36;
            a00 += *(const v4f*)&fs[sb];      a10 += *(const v4f*)&fs[sb + 4];
            a01 += *(const v4f*)&fs[sb + 8];  a11 += *(const v4f*)&fs[sb + 12];
            a02 += *(const v4f*)&fs[sb + 16]; a12 += *(const v4f*)&fs[sb + 20];
            a03 += *(const v4f*)&fs[sb + 24]; a13 += *(const v4f*)&fs[sb + 28];
        }
        float* __restrict__ ob = outg + b * OUTL;
        const v4f* accs[8] = {&a00, &a10, &a01, &a11, &a02, &a12, &a03, &a13};
#pragma unroll
        for (int uv = 0; uv < 8; ++uv) {
            int u = uv & 1, v = uv >> 1;
            int tb = T0 + 256 * u + 512 * v + 4 * q + 16 * ln16;
            v4f a = *accs[uv];
#pragma unroll
            for (int r2 = 0; r2 < 4; ++r2)
                if (tb + r2 < OUTL) ob[tb + r2] = a[r2];
        }
    }
}

extern "C" void kernel_launch(void* const* d_in, const int* in_sizes, int n_in,
                              void* d_out, int out_size, void* d_ws, size_t ws_size,
                              hipStream_t stream) {
    const float* x = (const float*)d_in[0];
    float* out = (float*)d_out;
    selfconv_mfma5<<<dim3(512), dim3(512), 0, stream>>>(x, out);
}

// Round 8
// 61.449 us; speedup vs baseline: 1.2076x; 1.0612x over previous
//
#include <hip/hip_runtime.h>

#define LL    4096
#define OUTL  8191
#define FPAD  272
#define NPDW  2336          // dwords per fwd copy: elements -272..4399
#define CB1   2352          // copy1 base (16-dw gap)
#define RB    4704          // rev-copy base dword
#define BTOP  5887          // rev top x-index (== 7 mod 8)
#define NGUP  992           // rev units, padded to /32 (data units 224..735)
#define LDSDW 9824          // contains benign prefetch overrun (max 9823)

typedef short v8s __attribute__((ext_vector_type(8)));
typedef float v4f __attribute__((ext_vector_type(4)));

__device__ __forceinline__ unsigned bf16b(float f) {
    unsigned u = __builtin_bit_cast(unsigned, f);
    u += 0x7fff + ((u >> 16) & 1);          // RNE
    return u >> 16;
}
__device__ __forceinline__ unsigned pk(float lo, float hi) {
    return bf16b(lo) | (bf16b(hi) << 16);
}
// unit swizzle: colliding lanes (g, g+8, g+16, g+24) -> XOR keys {0,2,4,6}
// => 4 distinct bank-quads; linear under +32k-unit strides (bits 3-4 preserved)
__device__ __forceinline__ int swz(int g) { return g ^ (((g >> 3) & 3) << 1); }

struct Frag {
    unsigned x0, x1, x2, x3, y0, y1, y2, y3;   // A tiles u=0,1 (4 dw each)
    uint4 b3, b2, b1, b0;                      // B tiles v=3..0 (load order)
};

__global__ __launch_bounds__(512, 4)
void selfconv_mfma6(const float* __restrict__ xg, float* __restrict__ outg) {
    __shared__ unsigned lds[LDSDW];
    const int tid = threadIdx.x;
    const int blk = blockIdx.x;
    const int b   = blk & 127;
    const int id  = blk >> 7;                       // light regions first
    const int rg  = (id == 0) ? 0 : (id == 1) ? 3 : (id == 2) ? 1 : 2;
    const int T0  = rg << 11;
    const float* __restrict__ xb = xg + b * LL;

    // ---- fwd staging: thread w covers elements E..E+8, E = 8w-272 ----
#pragma unroll
    for (int rr = 0; rr < 2; ++rr) {
        int w = tid + rr * 512;
        if (w < 584) {
            int E = 8 * w - FPAD;
            float e0,e1,e2,e3,e4,e5,e6,e7,e8;
            if (E >= 0 && E + 8 < LL) {             // fast: vector loads
                float4 fa = *(const float4*)(xb + E);
                float4 fb = *(const float4*)(xb + E + 4);
                e0=fa.x; e1=fa.y; e2=fa.z; e3=fa.w;
                e4=fb.x; e5=fb.y; e6=fb.z; e7=fb.w; e8=xb[E+8];
            } else {                                 // edges: guarded scalars
                float t[9];
#pragma unroll
                for (int k = 0; k < 9; ++k) {
                    int e = E + k;
                    t[k] = (e >= 0 && e < LL) ? xb[e] : 0.f;
                }
                e0=t[0]; e1=t[1]; e2=t[2]; e3=t[3]; e4=t[4];
                e5=t[5]; e6=t[6]; e7=t[7]; e8=t[8];
            }
            uint4 d0{pk(e0,e1), pk(e2,e3), pk(e4,e5), pk(e6,e7)};
            uint4 d1{pk(e1,e2), pk(e3,e4), pk(e5,e6), pk(e7,e8)};
            *(uint4*)&lds[4 * w]       = d0;
            *(uint4*)&lds[CB1 + 4 * w] = d1;
        }
    }
    // ---- rev staging: unit g holds yr[8g..8g+7] = x[BTOP-8g-7..BTOP-8g] ----
    {
        int g = 224 + tid;                          // in-range units, aligned
        int x0 = BTOP - 7 - 8 * g;                  // 0..4088, float4-aligned
        float4 fa = *(const float4*)(xb + x0);
        float4 fb = *(const float4*)(xb + x0 + 4);
        uint4 o{pk(fb.w, fb.z), pk(fb.y, fb.x), pk(fa.w, fa.z), pk(fa.y, fa.x)};
        *(uint4*)&lds[RB + 4 * swz(g)] = o;
    }
    // ---- zero rev pads: units [0,224) and [736,992) (swizzle-closed) ----
    if (tid < 480) {
        int u = (tid < 224) ? tid : tid + 512;
        *(uint4*)&lds[RB + 4 * u] = uint4{0, 0, 0, 0};
    }
    __syncthreads();

    const int wv = tid >> 6, lane = tid & 63, ln16 = lane & 15, q = lane >> 4;

    // i-union over the 8 tiles (A +256u, B +512v)
    int mn = 0x7fffffff, mx = -0x7fffffff;
#pragma unroll
    for (int u = 0; u < 2; ++u)
#pragma unroll
        for (int v = 0; v < 4; ++v) {
            int base = T0 + 256 * u + 512 * v;
            int iLo = base - (LL - 1); if (iLo < 0) iLo = 0;
            int iHi = base + 255;      if (iHi > LL - 1) iHi = LL - 1;
            int a = iLo - 256 * u; if (a < mn) mn = a;
            int c2 = iHi - 256 * u; if (c2 > mx) mx = c2;
        }
    const int base_   = mn - 15;
    const int i0start = base_ - ((base_ - 1) & 7);   // == 1 mod 8
    const int nch     = ((mx - i0start) >> 5) + 1;
    const int nw      = (nch - wv + 7) >> 3;         // 8-way interleaved split
    const int i0w     = i0start + 32 * wv;

    // A: x[i0 + m + 8q + j], m=ln16 — parity selects fwd copy
    const int s0p = i0w + ln16 + 8 * q + FPAD;
    const int aw  = (s0p >> 1) + ((s0p & 1) ? CB1 : 0);
    // B: yr unit base at v=3; subsequent strides all preserve the swizzle key
    const int g3 = (4352 - T0 + i0w - 16 * ln16 + 8 * q) >> 3;   // 4352=BTOP-1535
    const int bw = RB + 4 * swz(g3);

    v4f a00{0,0,0,0}, a01{0,0,0,0}, a02{0,0,0,0}, a03{0,0,0,0};
    v4f a10{0,0,0,0}, a11{0,0,0,0}, a12{0,0,0,0}, a13{0,0,0,0};

    auto ld = [&](Frag& F, int a, int w) {
        F.x0 = lds[a];       F.x1 = lds[a + 1];
        F.x2 = lds[a + 2];   F.x3 = lds[a + 3];
        F.y0 = lds[a + 128]; F.y1 = lds[a + 129];   // A tile u=1 (+256 elems)
        F.y2 = lds[a + 130]; F.y3 = lds[a + 131];
        F.b3 = *(const uint4*)&lds[w];
        F.b2 = *(const uint4*)&lds[w + 256];
        F.b1 = *(const uint4*)&lds[w + 512];
        F.b0 = *(const uint4*)&lds[w + 768];
    };
    auto mkA = [](unsigned u0, unsigned u1, unsigned u2, unsigned u3) {
        union { unsigned x[4]; v8s s; } z;
        z.x[0] = u0; z.x[1] = u1; z.x[2] = u2; z.x[3] = u3; return z.s;
    };
    auto mkB = [](uint4 v) {
        union { unsigned x[4]; v8s s; } z;
        z.x[0] = v.x; z.x[1] = v.y; z.x[2] = v.z; z.x[3] = v.w; return z.s;
    };
    auto cmp = [&](const Frag& F) {      // consume in load-age order: B3 first
        v8s A0 = mkA(F.x0, F.x1, F.x2, F.x3);
        v8s A1 = mkA(F.y0, F.y1, F.y2, F.y3);
        v8s B3 = mkB(F.b3), B2 = mkB(F.b2), B1 = mkB(F.b1), B0 = mkB(F.b0);
        a03 = __builtin_amdgcn_mfma_f32_16x16x32_bf16(A0, B3, a03, 0, 0, 0);
        a13 = __builtin_amdgcn_mfma_f32_16x16x32_bf16(A1, B3, a13, 0, 0, 0);
        a02 = __builtin_amdgcn_mfma_f32_16x16x32_bf16(A0, B2, a02, 0, 0, 0);
        a12 = __builtin_amdgcn_mfma_f32_16x16x32_bf16(A1, B2, a12, 0, 0, 0);
        a01 = __builtin_amdgcn_mfma_f32_16x16x32_bf16(A0, B1, a01, 0, 0, 0);
        a11 = __builtin_amdgcn_mfma_f32_16x16x32_bf16(A1, B1, a11, 0, 0, 0);
        a00 = __builtin_amdgcn_mfma_f32_16x16x32_bf16(A0, B0, a00, 0, 0, 0);
        a10 = __builtin_amdgcn_mfma_f32_16x16x32_bf16(A1, B0, a10, 0, 0, 0);
    };

    // wave-chunk stride: 256 elements = 128 A-dwords = 64 B-units
    Frag F0, F1;
    int awE = aw, bwE = bw, awO = aw + 128, bwO = bw + 128;
    ld(F0, awE, bwE); awE += 256; bwE += 256;
    ld(F1, awO, bwO); awO += 256; bwO += 256;
    int c = 0;
    for (; c + 2 < nw; c += 2) {
        cmp(F0); ld(F0, awE, bwE); awE += 256; bwE += 256;
        cmp(F1); ld(F1, awO, bwO); awO += 256; bwO += 256;
    }
    cmp(F0);
    if (c + 1 < nw) cmp(F1);

    // ---- 8-way reduction (3 stages), stride-36 scratch ----
    float* fs = (float*)lds;
    __syncthreads();
    if (wv >= 4) {
        int sb = (wv - 4) * 2304 + lane * 36;
        *(v4f*)&fs[sb]      = a00; *(v4f*)&fs[sb + 4]  = a10;
        *(v4f*)&fs[sb + 8]  = a01; *(v4f*)&fs[sb + 12] = a11;
        *(v4f*)&fs[sb + 16] = a02; *(v4f*)&fs[sb + 20] = a12;
        *(v4f*)&fs[sb + 24] = a03; *(v4f*)&fs[sb + 28] = a13;
    }
    __syncthreads();
    if (wv < 4) {
        int sb = wv * 2304 + lane * 36;
        a00 += *(const v4f*)&fs[sb];      a10 += *(const v4f*)&fs[sb + 4];
        a01 += *(const v4f*)&fs[sb + 8];  a11 += *(const v4f*)&fs[sb + 12];
        a02 += *(const v4f*)&fs[sb + 16]; a12 += *(const v4f*)&fs[sb + 20];
        a03 += *(const v4f*)&fs[sb + 24]; a13 += *(const v4f*)&fs[sb + 28];
    }
    __syncthreads();
    if (wv >= 1 && wv < 4) {
        int sb = (wv - 1) * 2304 + lane * 36;
        *(v4f*)&fs[sb]      = a00; *(v4f*)&fs[sb + 4]  = a10;
        *(v4f*)&fs[sb + 8]  = a01; *(v4f*)&fs[sb + 12] = a11;
        *(v4f*)&fs[sb + 16] = a02; *(v4f*)&fs[sb + 20] = a12;
        *(v4f*)&fs[sb + 24] = a03; *(v4f*)&fs[sb + 28] = a13;
    }
    __syncthreads();
    if (wv == 0) {
#pragma unroll
        for (int s = 0; s < 3; ++s) {
            int sb = s * 2304 + lane * 36;
            a00 += *(const v4f*)&fs[sb];      a10 += *(const v4f*)&fs[sb + 4];
            a01 += *(const v4f*)&fs[sb + 8];  a11 += *(const v4f*)&fs[sb + 12];
            a02 += *(const v4f*)&fs[sb + 16]; a12 += *(const v4f*)&fs[sb + 20];
            a03 += *(const v4f*)&fs[sb + 24]; a13 += *(const v4f*)&fs[sb + 28];
        }
        float* __restrict__ ob = outg + b * OUTL;
        const v4f* accs[8] = {&a00, &a10, &a01, &a11, &a02, &a12, &a03, &a13};
#pragma unroll
        for (int uv = 0; uv < 8; ++uv) {
            int u = uv & 1, v = uv >> 1;
            int tilebase = T0 + 256 * u + 512 * v;
            int tb = tilebase + 4 * q + 16 * ln16;
            v4f a = *accs[uv];
            if (tilebase + 255 < OUTL) {
                *(v4f*)&ob[tb] = a;                  // coalesced b128 store
            } else {
#pragma unroll
                for (int r2 = 0; r2 < 4; ++r2)
                    if (tb + r2 < OUTL) ob[tb + r2] = a[r2];
            }
        }
    }
}

extern "C" void kernel_launch(void* const* d_in, const int* in_sizes, int n_in,
                              void* d_out, int out_size, void* d_ws, size_t ws_size,
                              hipStream_t stream) {
    const float* x = (const float*)d_in[0];
    float* out = (float*)d_out;
    selfconv_mfma6<<<dim3(512), dim3(512), 0, stream>>>(x, out);
}